// Round 4
// baseline (68.100 us; speedup 1.0000x reference)
//
#include <hip/hip_runtime.h>
#include <math.h>

#define BB 4
#define CC 19
#define HH 512
#define WW 1024
#define NPIX (HH * WW)          // 524288 = 2^19
#define NB 160                  // histogram bins over max_prob in [0,1]
#define CONF_BIN 144            // 0.9 * 160 exactly -> bin>=144 <=> p>=0.9
#define FRACTION_F 0.66f
#define ROW (CC * NB)           // 3040 bins per image-block histogram
#define NROW (BB * CC)          // 76

#define NBLK1 512
#define BPI (NBLK1 / BB)        // 128 blocks per image
#define PPB (NPIX / BPI)        // 4096 pixels per block
#define T1 512                  // pass1 threads: 8 waves/block, 2 blocks/CU -> 4 waves/SIMD

// ws layout:
//   int   cntPart[NBLK1][ROW]   (6.23 MB)
//   float snlPart[NBLK1][ROW]   (6.23 MB)

__global__ __launch_bounds__(T1, 4) void st_pass1(const float* __restrict__ pred,
                                                  int* __restrict__ cntPart,
                                                  float* __restrict__ snlPart) {
    __shared__ int   hcnt[ROW];
    __shared__ float hsnl[ROW];
    int tid = threadIdx.x;
    for (int i = tid; i < ROW; i += T1) { hcnt[i] = 0; hsnl[i] = 0.f; }
    __syncthreads();

    int blk = blockIdx.x;
    int b   = blk >> 7;                  // / BPI
    int seg = blk & (BPI - 1);
    const float* base = pred + (size_t)b * CC * NPIX + (size_t)seg * PPB;

    #pragma unroll
    for (int it = 0; it < 2; ++it) {
        const float* bp = base + it * (T1 * 4) + tid * 4;
        float4 v[CC];
        #pragma unroll
        for (int c = 0; c < CC; ++c)
            v[c] = *(const float4*)(bp + (size_t)c * NPIX);

        #pragma unroll
        for (int j = 0; j < 4; ++j) {
            // component select folds at compile time (j unrolled) -> no scratch
            float x[CC];
            #pragma unroll
            for (int c = 0; c < CC; ++c) {
                float4 vv = v[c];
                x[c] = (j == 0) ? vv.x : (j == 1) ? vv.y : (j == 2) ? vv.z : vv.w;
            }
            // tree max: 19 -> 10 -> 5 -> 3 -> 1 (independent fmax ops)
            float t0[10];
            #pragma unroll
            for (int i = 0; i < 9; ++i) t0[i] = fmaxf(x[2*i], x[2*i+1]);
            t0[9] = x[18];
            float t1[5];
            #pragma unroll
            for (int i = 0; i < 5; ++i) t1[i] = fmaxf(t0[2*i], t0[2*i+1]);
            float m = fmaxf(fmaxf(fmaxf(t1[0], t1[1]), fmaxf(t1[2], t1[3])), t1[4]);
            // first-index argmax: downward overwrite (exact ties measure-zero)
            int arg = 0;
            #pragma unroll
            for (int c = CC - 1; c >= 1; --c) arg = (x[c] == m) ? c : arg;
            // 19 independent exps + tree sum
            float e[CC];
            #pragma unroll
            for (int c = 0; c < CC; ++c) e[c] = __expf(x[c] - m);
            float s0[10];
            #pragma unroll
            for (int i = 0; i < 9; ++i) s0[i] = e[2*i] + e[2*i+1];
            s0[9] = e[18];
            float s1[5];
            #pragma unroll
            for (int i = 0; i < 5; ++i) s1[i] = s0[2*i] + s0[2*i+1];
            float s = ((s1[0] + s1[1]) + (s1[2] + s1[3])) + s1[4];

            float prob = 1.f / s;            // max softmax prob
            float nll  = __logf(s);          // -log(max_prob)
            int bin = (int)(prob * (float)NB);
            bin = min(bin, NB - 1);
            int idx = arg * NB + bin;
            atomicAdd(&hcnt[idx], 1);        // LDS atomics: CU-local
            atomicAdd(&hsnl[idx], nll);
        }
    }
    __syncthreads();

    // flush private slice with plain coalesced stores
    int*   cp = cntPart + (size_t)blk * ROW;
    float* sp = snlPart + (size_t)blk * ROW;
    for (int i = tid; i < ROW; i += T1) { cp[i] = hcnt[i]; sp[i] = hsnl[i]; }
}

// One block per (b,c) row: accumulate 128 partial slices into LDS, parallel
// suffix-scan for the rank cutoff, atomicAdd the row's contribution to out.
__global__ __launch_bounds__(256) void st_pass2(const int* __restrict__ cntPart,
                                                const float* __restrict__ snlPart,
                                                float* __restrict__ out) {
    __shared__ int   scnt[NB];
    __shared__ float ssnl[NB];
    __shared__ int   sS[NB];
    __shared__ float sF[NB];
    __shared__ int   sBin;
    int tid = threadIdx.x;
    int r = blockIdx.x;                  // 0..75
    int b = r / CC, c = r - b * CC;

    if (tid < NB) { scnt[tid] = 0; ssnl[tid] = 0.f; }
    __syncthreads();

    const int*   cp = cntPart + (size_t)(b * BPI) * ROW + c * NB;
    const float* sp = snlPart + (size_t)(b * BPI) * ROW + c * NB;
    // 128 slices x 40 int4/float4 vectors, coalesced; ~2-way LDS atomic conflicts
    for (int e = tid; e < BPI * (NB / 4); e += 256) {
        int p = e / (NB / 4);
        int i = e - p * (NB / 4);
        int4   cv = *(const int4*)  (cp + (size_t)p * ROW + i * 4);
        float4 sv = *(const float4*)(sp + (size_t)p * ROW + i * 4);
        atomicAdd(&scnt[i*4+0], cv.x); atomicAdd(&scnt[i*4+1], cv.y);
        atomicAdd(&scnt[i*4+2], cv.z); atomicAdd(&scnt[i*4+3], cv.w);
        atomicAdd(&ssnl[i*4+0], sv.x); atomicAdd(&ssnl[i*4+1], sv.y);
        atomicAdd(&ssnl[i*4+2], sv.z); atomicAdd(&ssnl[i*4+3], sv.w);
    }
    __syncthreads();

    // inclusive suffix sums: sS[bin] = sum_{i>=bin} scnt[i], sF likewise
    if (tid < NB) { sS[tid] = scnt[tid]; sF[tid] = ssnl[tid]; }
    __syncthreads();
    for (int d = 1; d < NB; d <<= 1) {
        int   a = 0; float f = 0.f;
        if (tid < NB && tid + d < NB) { a = sS[tid + d]; f = sF[tid + d]; }
        __syncthreads();
        if (tid < NB) { sS[tid] += a; sF[tid] += f; }
        __syncthreads();
    }

    int count = sS[0];
    int k = (int)floorf((float)count * FRACTION_F);   // match jnp f32 math
    // boundary bin: largest bin with S(bin) >= k (unique crossing for k>=1)
    if (tid < NB) {
        int Sb  = sS[tid];
        int Sb1 = (tid + 1 < NB) ? sS[tid + 1] : 0;
        if (Sb >= k && Sb1 < k && k >= 1) sBin = tid;
    }
    __syncthreads();

    if (tid == 0) {
        float conf = sF[CONF_BIN];               // nll sum where p >= 0.9
        float sel;
        if (k <= 0) {
            sel = conf;
        } else {
            int Bn = sBin;
            if (Bn >= CONF_BIN) {
                sel = conf;                      // cutoff >= 0.9 -> union == {p>0.9}
            } else {
                int   cum  = (Bn + 1 < NB) ? sS[Bn + 1] : 0;
                float csum = (Bn + 1 < NB) ? sF[Bn + 1] : 0.f;
                float avg  = ssnl[Bn] / (float)max(scnt[Bn], 1);
                sel = csum + (float)(k - cum) * avg;
            }
        }
        atomicAdd(out, sel * (1.0f / (float)(BB * (size_t)NPIX)));
    }
}

extern "C" void kernel_launch(void* const* d_in, const int* in_sizes, int n_in,
                              void* d_out, int out_size, void* d_ws, size_t ws_size,
                              hipStream_t stream) {
    const float* pred = (const float*)d_in[0];
    float* out = (float*)d_out;

    char* ws = (char*)d_ws;
    int*   cntPart = (int*)ws;
    float* snlPart = (float*)(ws + (size_t)NBLK1 * ROW * sizeof(int));

    hipMemsetAsync(d_out, 0, sizeof(float), stream);   // out accumulated atomically
    st_pass1<<<NBLK1, T1, 0, stream>>>(pred, cntPart, snlPart);
    st_pass2<<<NROW, 256, 0, stream>>>(cntPart, snlPart, out);
}

// Round 5
// 45.803 us; speedup vs baseline: 1.4868x; 1.4868x over previous
//
#include <hip/hip_runtime.h>
#include <math.h>

#define BB 4
#define CC 19
#define HH 512
#define WW 1024
#define NPIX (HH * WW)          // 524288 = 2^19
#define NB 80                   // histogram bins over max_prob in [0,1]
#define CONF_BIN 72             // 0.9 * 80 exactly -> bin>=72 <=> p>=0.9
#define FRACTION_F 0.66f
#define ROW (CC * NB)           // 1520 bins per image-block histogram
#define NROW (BB * CC)          // 76

#define NBLK1 512
#define BPI (NBLK1 / BB)        // 128 blocks per image
#define PPB (NPIX / BPI)        // 4096 pixels per block
#define T1 512                  // 8 waves/block, 2 blocks/CU -> 4 waves/SIMD

// ws layout:
//   int   cntPart[NBLK1][ROW]   (3.11 MB)
//   float snlPart[NBLK1][ROW]   (3.11 MB)
//   float selbuf[NROW]

static __device__ __forceinline__ float comp(float4 v, int j) {
    // j is compile-time constant after unroll -> folds to .x/.y/.z/.w
    return (j == 0) ? v.x : (j == 1) ? v.y : (j == 2) ? v.z : v.w;
}

__global__ __launch_bounds__(T1, 4) void st_pass1(const float* __restrict__ pred,
                                                  int* __restrict__ cntPart,
                                                  float* __restrict__ snlPart) {
    __shared__ int   hcnt[ROW];
    __shared__ float hsnl[ROW];
    int tid = threadIdx.x;
    for (int i = tid; i < ROW; i += T1) { hcnt[i] = 0; hsnl[i] = 0.f; }
    __syncthreads();

    int blk = blockIdx.x;
    int b   = blk >> 7;                  // / BPI
    int seg = blk & (BPI - 1);
    const float* base = pred + (size_t)b * CC * NPIX + (size_t)seg * PPB;

    #pragma unroll
    for (int it = 0; it < 2; ++it) {
        const float* bp = base + it * (T1 * 4) + tid * 4;
        float4 v0[5], v1[5], v2[5], v3[4];

        // software pipeline: keep the next channel-group's loads in flight
        // while the online-logsumexp consumes the previous group.
        #pragma unroll
        for (int i = 0; i < 5; ++i) v0[i] = *(const float4*)(bp + (size_t)i * NPIX);
        #pragma unroll
        for (int i = 0; i < 5; ++i) v1[i] = *(const float4*)(bp + (size_t)(5 + i) * NPIX);
        asm volatile("" ::: "memory");   // pin load issue before compute below

        float m[4], s[4]; int arg[4];
        #pragma unroll
        for (int j = 0; j < 4; ++j) { m[j] = comp(v0[0], j); s[j] = 1.f; arg[j] = 0; }

#define PROC(VA, NCH, CBASE, START)                                   \
        _Pragma("unroll")                                             \
        for (int i = START; i < NCH; ++i) {                           \
            _Pragma("unroll")                                         \
            for (int j = 0; j < 4; ++j) {                             \
                float x  = comp(VA[i], j);                            \
                float nm = fmaxf(m[j], x);                            \
                s[j] = s[j] * __expf(m[j] - nm) + __expf(x - nm);     \
                arg[j] = (x > m[j]) ? (CBASE + i) : arg[j];           \
                m[j] = nm;                                            \
            }                                                         \
        }

        PROC(v0, 5, 0, 1)                // channels 1..4 (0 seeded init)
        #pragma unroll
        for (int i = 0; i < 5; ++i) v2[i] = *(const float4*)(bp + (size_t)(10 + i) * NPIX);
        asm volatile("" ::: "memory");
        PROC(v1, 5, 5, 0)                // channels 5..9
        #pragma unroll
        for (int i = 0; i < 4; ++i) v3[i] = *(const float4*)(bp + (size_t)(15 + i) * NPIX);
        asm volatile("" ::: "memory");
        PROC(v2, 5, 10, 0)               // channels 10..14
        PROC(v3, 4, 15, 0)               // channels 15..18
#undef PROC

        #pragma unroll
        for (int j = 0; j < 4; ++j) {
            float prob = 1.f / s[j];     // max softmax prob
            float nll  = __logf(s[j]);   // -log(max_prob)
            int bin = (int)(prob * (float)NB);
            bin = min(bin, NB - 1);
            int idx = arg[j] * NB + bin;
            atomicAdd(&hcnt[idx], 1);    // LDS atomics: CU-local
            atomicAdd(&hsnl[idx], nll);
        }
    }
    __syncthreads();

    // flush private slice with plain coalesced stores
    int*   cp = cntPart + (size_t)blk * ROW;
    float* sp = snlPart + (size_t)blk * ROW;
    for (int i = tid; i < ROW; i += T1) { cp[i] = hcnt[i]; sp[i] = hsnl[i]; }
}

// One block per (b,c) row: 80 threads sum the 128 partials (coalesced,
// 2 accumulator streams), thread 0 does the 80-bin cutoff scan.
__global__ __launch_bounds__(128) void st_pass2(const int* __restrict__ cntPart,
                                                const float* __restrict__ snlPart,
                                                float* __restrict__ selbuf) {
    __shared__ int   scnt[NB];
    __shared__ float ssnl[NB];
    int r = blockIdx.x;                  // 0..75
    int b = r / CC, c = r - b * CC;
    int tid = threadIdx.x;

    if (tid < NB) {
        size_t off = (size_t)(b * BPI) * ROW + (size_t)(c * NB + tid);
        int cs0 = 0, cs1 = 0; float ss0 = 0.f, ss1 = 0.f;
        #pragma unroll 8
        for (int p = 0; p < BPI; p += 2) {
            cs0 += cntPart[off + (size_t)p * ROW];
            cs1 += cntPart[off + (size_t)(p + 1) * ROW];
            ss0 += snlPart[off + (size_t)p * ROW];
            ss1 += snlPart[off + (size_t)(p + 1) * ROW];
        }
        scnt[tid] = cs0 + cs1;
        ssnl[tid] = ss0 + ss1;
    }
    __syncthreads();

    if (tid == 0) {
        int count = 0;
        #pragma unroll 8
        for (int i = 0; i < NB; ++i) count += scnt[i];
        float conf = 0.f;                // sum of nll where p >= 0.9
        #pragma unroll 8
        for (int i = CONF_BIN; i < NB; ++i) conf += ssnl[i];
        int k = (int)floorf((float)count * FRACTION_F);  // match jnp f32 math
        float sel;
        if (k == 0) {
            sel = conf;
        } else {
            int cum = 0;                 // count in bins strictly above boundary
            float csum = 0.f;
            int bin = NB - 1;
            int hh = 0;
            for (; bin >= 0; --bin) {
                hh = scnt[bin];
                if (cum + hh >= k) break;    // rank k-1 lies in this bin
                cum += hh;
                csum += ssnl[bin];
            }
            if (bin < 0) {
                sel = csum;              // safety (k < count always)
            } else if (bin >= CONF_BIN) {
                sel = conf;              // cutoff >= 0.9 -> union == {p>0.9}
            } else {
                float avg = ssnl[bin] / (float)max(hh, 1);
                sel = csum + (float)(k - cum) * avg;
            }
        }
        selbuf[r] = sel;
    }
}

__global__ __launch_bounds__(128) void st_pass3(const float* __restrict__ selbuf,
                                                float* __restrict__ out) {
    __shared__ float red[128];
    int t = threadIdx.x;
    red[t] = (t < NROW) ? selbuf[t] : 0.f;
    __syncthreads();
    for (int off = 64; off > 0; off >>= 1) {
        if (t < off) red[t] += red[t + off];
        __syncthreads();
    }
    if (t == 0) out[0] = red[0] * (1.0f / (float)(BB * (size_t)NPIX));
}

extern "C" void kernel_launch(void* const* d_in, const int* in_sizes, int n_in,
                              void* d_out, int out_size, void* d_ws, size_t ws_size,
                              hipStream_t stream) {
    const float* pred = (const float*)d_in[0];
    float* out = (float*)d_out;

    char* ws = (char*)d_ws;
    int*   cntPart = (int*)ws;
    float* snlPart = (float*)(ws + (size_t)NBLK1 * ROW * sizeof(int));
    float* selbuf  = (float*)(ws + (size_t)NBLK1 * ROW * (sizeof(int) + sizeof(float)));

    st_pass1<<<NBLK1, T1, 0, stream>>>(pred, cntPart, snlPart);
    st_pass2<<<NROW, 128, 0, stream>>>(cntPart, snlPart, selbuf);
    st_pass3<<<1, 128, 0, stream>>>(selbuf, out);
}

// Round 6
// 41.633 us; speedup vs baseline: 1.6357x; 1.1002x over previous
//
#include <hip/hip_runtime.h>
#include <math.h>

#define BB 4
#define CC 19
#define HH 512
#define WW 1024
#define NPIX (HH * WW)          // 524288 = 2^19
#define NB 80                   // histogram bins over max_prob in [0,1]
#define CONF_BIN 72             // 0.9 * 80 exactly -> bin>=72 <=> p>=0.9
#define FRACTION_F 0.66f
#define ROW (CC * NB)           // 1520 bins per image-block histogram
#define NROW (BB * CC)          // 76

#define NBLK1 512
#define BPI (NBLK1 / BB)        // 128 blocks per image
#define PPB (NPIX / BPI)        // 4096 pixels per block
#define T1 512                  // 8 waves/block, 2 blocks/CU -> 4 waves/SIMD

// ws layout:
//   int   cntPart[NBLK1][ROW]   (3.11 MB)
//   float snlPart[NBLK1][ROW]   (3.11 MB)

static __device__ __forceinline__ float comp(float4 v, int j) {
    return (j == 0) ? v.x : (j == 1) ? v.y : (j == 2) ? v.z : v.w;
}

__global__ __launch_bounds__(T1, 4) void st_pass1(const float* __restrict__ pred,
                                                  int* __restrict__ cntPart,
                                                  float* __restrict__ snlPart,
                                                  float* __restrict__ out) {
    __shared__ int   hcnt[ROW];
    __shared__ float hsnl[ROW];
    int tid = threadIdx.x;
    if (blockIdx.x == 0 && tid == 0) out[0] = 0.f;   // pass2 accumulates atomically
    for (int i = tid; i < ROW; i += T1) { hcnt[i] = 0; hsnl[i] = 0.f; }
    __syncthreads();

    int blk = blockIdx.x;
    int b   = blk >> 7;                  // / BPI
    int seg = blk & (BPI - 1);
    const float* bp0 = pred + (size_t)b * CC * NPIX + (size_t)seg * PPB + tid * 4;
    const float* bp1 = bp0 + T1 * 4;     // second half of this block's segment

    float4 va[5], vb[5], vc[5], vd[4];
    float m[4], s[4]; int arg[4];

#define LOAD5(DST, BP, C0)                                            \
        _Pragma("unroll")                                             \
        for (int i = 0; i < 5; ++i)                                   \
            DST[i] = *(const float4*)((BP) + (size_t)(C0 + i) * NPIX);
#define LOAD4(DST, BP, C0)                                            \
        _Pragma("unroll")                                             \
        for (int i = 0; i < 4; ++i)                                   \
            DST[i] = *(const float4*)((BP) + (size_t)(C0 + i) * NPIX);
#define FENCE asm volatile("" ::: "memory")
#define INIT4(VA)                                                     \
        _Pragma("unroll")                                             \
        for (int j = 0; j < 4; ++j) { m[j] = comp(VA[0], j); s[j] = 1.f; arg[j] = 0; }
#define PROC(VA, NCH, CBASE, START)                                   \
        _Pragma("unroll")                                             \
        for (int i = START; i < NCH; ++i) {                           \
            _Pragma("unroll")                                         \
            for (int j = 0; j < 4; ++j) {                             \
                float x  = comp(VA[i], j);                            \
                float nm = fmaxf(m[j], x);                            \
                s[j] = s[j] * __expf(m[j] - nm) + __expf(x - nm);     \
                arg[j] = (x > m[j]) ? (CBASE + i) : arg[j];           \
                m[j] = nm;                                            \
            }                                                         \
        }
#define FINAL()                                                       \
        _Pragma("unroll")                                             \
        for (int j = 0; j < 4; ++j) {                                 \
            float prob = 1.f / s[j];                                  \
            float nll  = __logf(s[j]);                                \
            int bin = min((int)(prob * (float)NB), NB - 1);           \
            int idx = arg[j] * NB + bin;                              \
            atomicAdd(&hcnt[idx], 1);                                 \
            atomicAdd(&hsnl[idx], nll);                               \
        }

    // 8-group rolling pipeline across BOTH iterations: loads never drain.
    LOAD5(va, bp0, 0); LOAD5(vb, bp0, 5); FENCE;
    INIT4(va)
    PROC(va, 5, 0, 1)
    LOAD5(vc, bp0, 10); FENCE;
    PROC(vb, 5, 5, 0)
    LOAD4(vd, bp0, 15); FENCE;
    PROC(vc, 5, 10, 0)
    LOAD5(va, bp1, 0); FENCE;            // prefetch iter2 g0 before last PROC
    PROC(vd, 4, 15, 0)
    FINAL()                              // iter1 atomics overlap iter2 loads
    LOAD5(vb, bp1, 5); FENCE;
    INIT4(va)
    PROC(va, 5, 0, 1)
    LOAD5(vc, bp1, 10); FENCE;
    PROC(vb, 5, 5, 0)
    LOAD4(vd, bp1, 15); FENCE;
    PROC(vc, 5, 10, 0)
    PROC(vd, 4, 15, 0)
    FINAL()
#undef LOAD5
#undef LOAD4
#undef FENCE
#undef INIT4
#undef PROC
#undef FINAL
    __syncthreads();

    // flush private slice with plain coalesced stores
    int*   cp = cntPart + (size_t)blk * ROW;
    float* sp = snlPart + (size_t)blk * ROW;
    for (int i = tid; i < ROW; i += T1) { cp[i] = hcnt[i]; sp[i] = hsnl[i]; }
}

// Fused tail: one block per (b,c) row. 4 threads per bin sum 32 partials each
// (coalesced), LDS combine, thread 0 scans for the rank cutoff and atomically
// adds the row's contribution to out[0] (zeroed by pass1).
__global__ __launch_bounds__(384) void st_pass2(const int* __restrict__ cntPart,
                                                const float* __restrict__ snlPart,
                                                float* __restrict__ out) {
    __shared__ int   pcnt[4][NB];
    __shared__ float psnl[4][NB];
    __shared__ int   scnt[NB];
    __shared__ float ssnl[NB];
    int r = blockIdx.x;                  // 0..75
    int b = r / CC, c = r - b * CC;
    int tid = threadIdx.x;

    if (tid < 4 * NB) {
        int q   = tid / NB;              // partial-quarter 0..3
        int bin = tid - q * NB;
        size_t off = (size_t)(b * BPI + q * 32) * ROW + (size_t)(c * NB + bin);
        int cs0 = 0, cs1 = 0; float ss0 = 0.f, ss1 = 0.f;
        #pragma unroll 8
        for (int p = 0; p < 32; p += 2) {
            cs0 += cntPart[off + (size_t)p * ROW];
            cs1 += cntPart[off + (size_t)(p + 1) * ROW];
            ss0 += snlPart[off + (size_t)p * ROW];
            ss1 += snlPart[off + (size_t)(p + 1) * ROW];
        }
        pcnt[q][bin] = cs0 + cs1;
        psnl[q][bin] = ss0 + ss1;
    }
    __syncthreads();
    if (tid < NB) {
        scnt[tid] = (pcnt[0][tid] + pcnt[1][tid]) + (pcnt[2][tid] + pcnt[3][tid]);
        ssnl[tid] = (psnl[0][tid] + psnl[1][tid]) + (psnl[2][tid] + psnl[3][tid]);
    }
    __syncthreads();

    if (tid == 0) {
        int count = 0;
        #pragma unroll 8
        for (int i = 0; i < NB; ++i) count += scnt[i];
        float conf = 0.f;                // sum of nll where p >= 0.9
        #pragma unroll 8
        for (int i = CONF_BIN; i < NB; ++i) conf += ssnl[i];
        int k = (int)floorf((float)count * FRACTION_F);  // match jnp f32 math
        float sel;
        if (k == 0) {
            sel = conf;
        } else {
            int cum = 0;                 // count in bins strictly above boundary
            float csum = 0.f;
            int bin = NB - 1;
            int hh = 0;
            for (; bin >= 0; --bin) {
                hh = scnt[bin];
                if (cum + hh >= k) break;    // rank k-1 lies in this bin
                cum += hh;
                csum += ssnl[bin];
            }
            if (bin < 0) {
                sel = csum;              // safety (k < count always)
            } else if (bin >= CONF_BIN) {
                sel = conf;              // cutoff >= 0.9 -> union == {p>0.9}
            } else {
                float avg = ssnl[bin] / (float)max(hh, 1);
                sel = csum + (float)(k - cum) * avg;
            }
        }
        atomicAdd(out, sel * (1.0f / (float)(BB * (size_t)NPIX)));
    }
}

extern "C" void kernel_launch(void* const* d_in, const int* in_sizes, int n_in,
                              void* d_out, int out_size, void* d_ws, size_t ws_size,
                              hipStream_t stream) {
    const float* pred = (const float*)d_in[0];
    float* out = (float*)d_out;

    char* ws = (char*)d_ws;
    int*   cntPart = (int*)ws;
    float* snlPart = (float*)(ws + (size_t)NBLK1 * ROW * sizeof(int));

    st_pass1<<<NBLK1, T1, 0, stream>>>(pred, cntPart, snlPart, out);
    st_pass2<<<NROW, 384, 0, stream>>>(cntPart, snlPart, out);
}